// Round 10
// baseline (315.595 us; speedup 1.0000x reference)
//
#include <hip/hip_runtime.h>
#include <hip/hip_bf16.h>
#include <math.h>

#define Cch 64
#define Hh  256
#define Ww  256
#define HW  (Hh * Ww)

// ws layout (32-bit words):
// [0, 4608): A-frags [18 steps][64 lanes][4 u32]  (single bf16, packed pairs)
#define WS_WC2  4608     // [16][16] f32 conv2 center taps
#define WS_SC   4864     // [16] BN scale
#define WS_OFF  4880     // [16] BN offset (incl conv2 bias)

typedef __attribute__((ext_vector_type(8))) short bf16x8;
typedef __attribute__((ext_vector_type(4))) float f32x4;

__device__ __forceinline__ float mishf(float x) {
    float e  = __expf(fminf(x, 15.0f));
    float n  = 1.0f + e;
    float n2 = n * n;
    float t  = __fdividef(n2 - 1.0f, n2 + 1.0f);
    return x > 15.0f ? x : x * t;
}

__device__ __forceinline__ unsigned packbf(float a, float b) {
    unsigned short ua = __builtin_bit_cast(unsigned short, __float2bfloat16(a));
    unsigned short ub = __builtin_bit_cast(unsigned short, __float2bfloat16(b));
    return (unsigned)ua | ((unsigned)ub << 16);
}

// A value for (output m, step s, quarter q, j):
// s<16: channel c=16q+s; j<3 -> m_kh(kw=j) col 36+c*3+j; j in 3..5 -> m_kw col
// 228+c*3+(j-3); j>=6 -> 0.  s==16: gc k=j (col q*9+j).  s==17: j==0 -> gc k=8.
__device__ __forceinline__ float conv1_wval2(const float* w1, int m, int s,
                                             int q, int j) {
    if (s < 16) {
        int c = 16 * q + s;
        if (j < 3) return w1[m * 420 + 36 + c * 3 + j];
        if (j < 6) return w1[m * 420 + 228 + c * 3 + (j - 3)];
        return 0.0f;
    } else if (s == 16) {
        return w1[m * 420 + q * 9 + j];
    }
    return (j == 0) ? w1[m * 420 + q * 9 + 8] : 0.0f;
}

__global__ __launch_bounds__(256) void prep_kernel(
    const float* __restrict__ w1, const float* __restrict__ w2,
    const float* __restrict__ b2,
    const float* __restrict__ gamma, const float* __restrict__ beta,
    const float* __restrict__ mean,  const float* __restrict__ var,
    float* __restrict__ ws)
{
    unsigned* wsu = (unsigned*)ws;
    const int tid = threadIdx.x;

    // A-frags: lane holds A[m=lane&15][k=8q+j], q=lane>>4 (single bf16)
    for (int idx = tid; idx < 1152; idx += 256) {
        int s = idx >> 6, lane = idx & 63;
        int m = lane & 15, q = lane >> 4;
        #pragma unroll
        for (int jp = 0; jp < 4; ++jp) {
            float v0 = conv1_wval2(w1, m, s, q, 2 * jp);
            float v1 = conv1_wval2(w1, m, s, q, 2 * jp + 1);
            wsu[idx * 4 + jp] = packbf(v0, v1);
        }
    }

    for (int idx = tid; idx < 256; idx += 256) {
        int o = idx / 16, i = idx % 16;
        ws[WS_WC2 + idx] = w2[o * 144 + i * 9 + 4];
    }
    if (tid < 16) {
        float sc = gamma[tid] * rsqrtf(var[tid] + 1e-5f);
        ws[WS_SC + tid]  = sc;
        ws[WS_OFF + tid] = b2[tid] * sc + beta[tid] - mean[tid] * sc;
    }
}

#define LDS_FENCE() do {                                             \
    asm volatile("s_waitcnt lgkmcnt(0)" ::: "memory");               \
    __builtin_amdgcn_sched_barrier(0);                               \
} while (0)

#define LOAD9(dst, cb) do {                                          \
    const float* r0_ = (cb) + (size_t)hmc * Ww + w;                  \
    const float* r1_ = (cb) + (size_t)h   * Ww + w;                  \
    const float* r2_ = (cb) + (size_t)hpc * Ww + w;                  \
    (dst)[0] = r0_[offm]; (dst)[1] = r0_[0]; (dst)[2] = r0_[offp];   \
    (dst)[3] = r1_[offm]; (dst)[4] = r1_[0]; (dst)[5] = r1_[offp];   \
    (dst)[6] = r2_[offm]; (dst)[7] = r2_[0]; (dst)[8] = r2_[offp];   \
} while (0)

#define MASK9IP(p) do {                                              \
    (p)[0] = (okhm && okm) ? (p)[0] : 0.0f;                          \
    (p)[1] =  okhm         ? (p)[1] : 0.0f;                          \
    (p)[2] = (okhm && okp) ? (p)[2] : 0.0f;                          \
    (p)[3] =  okm          ? (p)[3] : 0.0f;                          \
    (p)[5] =  okp          ? (p)[5] : 0.0f;                          \
    (p)[6] = (okhp && okm) ? (p)[6] : 0.0f;                          \
    (p)[7] =  okhp         ? (p)[7] : 0.0f;                          \
    (p)[8] = (okhp && okp) ? (p)[8] : 0.0f;                          \
} while (0)

__device__ __forceinline__ float dot4(f32x4 a, f32x4 b) {
    float r = a[0] * b[0];
    r = fmaf(a[1], b[1], r);
    r = fmaf(a[2], b[2], r);
    r = fmaf(a[3], b[3], r);
    return r;
}

__global__ __launch_bounds__(256, 4) void revo_kernel(
    const float* __restrict__ in,
    const float* __restrict__ b1,
    const float* __restrict__ w3, const float* __restrict__ b3,
    const float* __restrict__ ws,
    float* __restrict__ out)
{
    const int tid = threadIdx.x;
    const int t   = tid >> 6;          // wave id (0..3): 16-pixel sub-segment
    const int l   = tid & 63;
    const int q   = l >> 4;            // channel-group of this lane
    const int px  = l & 15;            // pixel-in-tile

    const int bid     = blockIdx.x;
    const int logical = ((bid & 7) << 8) + (bid >> 3);  // XCD-chunked
    const int wseg = logical & 3;
    const int h    = (logical >> 2) & (Hh - 1);
    const int b    = logical >> 10;
    const int w    = wseg * 64 + t * 16 + px;

    __shared__ uint4 Alds[1152];       // 18 KB: A-frags, shared by all 4 waves
    __shared__ f32x4 ldsf[4][16][5];   // wave-private exchange (fence-only)

    // stage A-frags once per block (coalesced b128, conflict-free)
    {
        const uint4* wa = (const uint4*)ws;
        #pragma unroll
        for (int i = 0; i < 5; ++i) {
            int idx = tid + 256 * i;
            if (idx < 1152) Alds[idx] = wa[idx];
        }
    }
    __syncthreads();

    const float* base_c = in + ((size_t)b * Cch + 16 * q) * HW;

    const bool okm = (w > 0);
    const bool okp = (w < Ww - 1);
    const int offm = okm ? -1 : 0;
    const int offp = okp ?  1 : 0;

    const int hm = h - 1, hp = h + 1;
    const bool okhm = (hm >= 0), okhp = (hp < Hh);
    const int hmc = okhm ? hm : 0;
    const int hpc = okhp ? hp : Hh - 1;

    // ======= conv1: 16 channel-steps + 2 gmax-steps, B built in registers ===
    f32x4 acc = (f32x4){0.f, 0.f, 0.f, 0.f};
    float gmax[9];
    float pT[9], pN[9];

    LOAD9(pT, base_c);                 // channel 16q+0
    #pragma unroll
    for (int s = 0; s < 16; ++s) {
        if (s < 15) LOAD9(pN, base_c + (size_t)(s + 1) * HW);
        MASK9IP(pT);
        if (s == 0) {
            #pragma unroll
            for (int k = 0; k < 9; ++k) gmax[k] = pT[k];
        } else {
            #pragma unroll
            for (int k = 0; k < 9; ++k) gmax[k] = fmaxf(gmax[k], pT[k]);
        }
        float mkh0 = fmaxf(fmaxf(pT[0], pT[3]), pT[6]);
        float mkh1 = fmaxf(fmaxf(pT[1], pT[4]), pT[7]);
        float mkh2 = fmaxf(fmaxf(pT[2], pT[5]), pT[8]);
        float mkw0 = fmaxf(fmaxf(pT[0], pT[1]), pT[2]);
        float mkw1 = fmaxf(fmaxf(pT[3], pT[4]), pT[5]);
        float mkw2 = fmaxf(fmaxf(pT[6], pT[7]), pT[8]);

        uint4 bv;
        bv.x = packbf(mkh0, mkh1);
        bv.y = packbf(mkh2, mkw0);
        bv.z = packbf(mkw1, mkw2);
        bv.w = 0u;

        uint4 Ah = Alds[s * 64 + l];
        acc = __builtin_amdgcn_mfma_f32_16x16x32_bf16(
            __builtin_bit_cast(bf16x8, Ah), __builtin_bit_cast(bf16x8, bv),
            acc, 0, 0, 0);

        #pragma unroll
        for (int k = 0; k < 9; ++k) pT[k] = pN[k];
    }
    {   // gmax steps 16,17
        uint4 bv;
        bv.x = packbf(gmax[0], gmax[1]);
        bv.y = packbf(gmax[2], gmax[3]);
        bv.z = packbf(gmax[4], gmax[5]);
        bv.w = packbf(gmax[6], gmax[7]);
        uint4 Ah = Alds[16 * 64 + l];
        acc = __builtin_amdgcn_mfma_f32_16x16x32_bf16(
            __builtin_bit_cast(bf16x8, Ah), __builtin_bit_cast(bf16x8, bv),
            acc, 0, 0, 0);
        uint4 bv2;
        bv2.x = packbf(gmax[8], 0.0f);
        bv2.y = 0u; bv2.z = 0u; bv2.w = 0u;
        uint4 Ah2 = Alds[17 * 64 + l];
        acc = __builtin_amdgcn_mfma_f32_16x16x32_bf16(
            __builtin_bit_cast(bf16x8, Ah2), __builtin_bit_cast(bf16x8, bv2),
            acc, 0, 0, 0);
    }

    // acc[j] = y[o=4q+j][px] complete. ======= epilogue, split across q ======
    f32x4 b1q = ((const f32x4*)b1)[q];
    f32x4 fp;
    #pragma unroll
    for (int j = 0; j < 4; ++j) fp[j] = mishf(acc[j] + b1q[j]);

    ldsf[t][px][q] = fp;
    LDS_FENCE();
    f32x4 F0 = ldsf[t][px][0], F1 = ldsf[t][px][1],
          F2 = ldsf[t][px][2], F3 = ldsf[t][px][3];
    LDS_FENCE();

    // conv2 rows o=4q..4q+3 + folded BN + mish gate
    const f32x4* wc2v = (const f32x4*)(ws + WS_WC2);
    f32x4 scq  = ((const f32x4*)(ws + WS_SC))[q];
    f32x4 offq = ((const f32x4*)(ws + WS_OFF))[q];
    f32x4 f2p;
    #pragma unroll
    for (int j = 0; j < 4; ++j) {
        int o = 4 * q + j;
        float a2 = dot4(wc2v[o * 4 + 0], F0) + dot4(wc2v[o * 4 + 1], F1)
                 + dot4(wc2v[o * 4 + 2], F2) + dot4(wc2v[o * 4 + 3], F3);
        f2p[j] = fp[j] * mishf(a2 * scq[j] + offq[j]);
    }

    ldsf[t][px][q] = f2p;
    LDS_FENCE();
    f32x4 G0 = ldsf[t][px][0], G1 = ldsf[t][px][1],
          G2 = ldsf[t][px][2], G3 = ldsf[t][px][3];
    LDS_FENCE();

    // conv3: this group's 9 logits + softmax
    const f32x4* w3v = (const f32x4*)w3;
    float att[9];
    {
        float mx = -1e30f;
        #pragma unroll
        for (int k = 0; k < 9; ++k) {
            int row = q * 9 + k;
            float a2 = b3[row];
            a2 += dot4(w3v[row * 4 + 0], G0) + dot4(w3v[row * 4 + 1], G1)
                + dot4(w3v[row * 4 + 2], G2) + dot4(w3v[row * 4 + 3], G3);
            att[k] = a2;
            mx = fmaxf(mx, a2);
        }
        float sum = 0.0f;
        #pragma unroll
        for (int k = 0; k < 9; ++k) { att[k] = __expf(att[k] - mx); sum += att[k]; }
        float inv = __fdividef(1.0f, sum);
        #pragma unroll
        for (int k = 0; k < 9; ++k) att[k] *= inv;
    }

    // ======= aggregation: this group's 16 channels, 1-ahead pipeline ========
    float* ob = out + (((size_t)b * Cch + 16 * q) * Hh + h) * Ww + w;
    LOAD9(pT, base_c);
    #pragma unroll
    for (int cc = 0; cc < 16; ++cc) {
        if (cc < 15) LOAD9(pN, base_c + (size_t)(cc + 1) * HW);
        float a2 = 0.0f;
        a2 = fmaf((okhm && okm) ? pT[0] : 0.0f, att[0], a2);
        a2 = fmaf( okhm         ? pT[1] : 0.0f, att[1], a2);
        a2 = fmaf((okhm && okp) ? pT[2] : 0.0f, att[2], a2);
        a2 = fmaf( okm          ? pT[3] : 0.0f, att[3], a2);
        a2 = fmaf( pT[4],                       att[4], a2);
        a2 = fmaf( okp          ? pT[5] : 0.0f, att[5], a2);
        a2 = fmaf((okhp && okm) ? pT[6] : 0.0f, att[6], a2);
        a2 = fmaf( okhp         ? pT[7] : 0.0f, att[7], a2);
        a2 = fmaf((okhp && okp) ? pT[8] : 0.0f, att[8], a2);
        ob[(size_t)cc * HW] = a2;
        #pragma unroll
        for (int k = 0; k < 9; ++k) pT[k] = pN[k];
    }
}

extern "C" void kernel_launch(void* const* d_in, const int* in_sizes, int n_in,
                              void* d_out, int out_size, void* d_ws, size_t ws_size,
                              hipStream_t stream) {
    const float* in    = (const float*)d_in[0];
    const float* w1    = (const float*)d_in[1];
    const float* b1    = (const float*)d_in[2];
    const float* w2    = (const float*)d_in[3];
    const float* b2    = (const float*)d_in[4];
    const float* w3    = (const float*)d_in[5];
    const float* b3    = (const float*)d_in[6];
    const float* gamma = (const float*)d_in[7];
    const float* beta  = (const float*)d_in[8];
    const float* mean  = (const float*)d_in[9];
    const float* var   = (const float*)d_in[10];
    float* out = (float*)d_out;
    float* ws  = (float*)d_ws;

    hipLaunchKernelGGL(prep_kernel, dim3(1), dim3(256), 0, stream,
                       w1, w2, b2, gamma, beta, mean, var, ws);

    hipLaunchKernelGGL(revo_kernel, dim3(2048), dim3(256), 0, stream,
                       in, b1, w3, b3, ws, out);
}